// Round 1
// baseline (3813.164 us; speedup 1.0000x reference)
//
#include <hip/hip_runtime.h>
#include <math.h>

#define HD 128
#define NEG 0.01f
#define GD 64

__device__ __forceinline__ float act_apply(float v, int act) {
    if (act == 1) return v > 0.f ? v : v * NEG;          // leaky relu
    if (act == 2) return 1.f / (1.f + __expf(-v));       // sigmoid
    if (act == 3) return tanhf(v);                       // tanh
    return v;
}

// C[M x 128] = act( A[M x 128] @ B (+bias) (+ addb [⊙ mulb]) )
// transB=0: B row-major [128 x 128], C=A@B.  transB=1: B row-major [128out x 128in], C=A@B^T.
__global__ __launch_bounds__(256) void gemm128(
    const float* __restrict__ A, const float* __restrict__ B,
    const float* __restrict__ bias, const float* __restrict__ addb,
    const float* __restrict__ mulb, float* __restrict__ C,
    int M, int act, int transB)
{
    __shared__ float As[16][68];
    __shared__ float Bs[16][68];
    const int tid = threadIdx.x;
    const int r0 = blockIdx.x * 64;
    const int c0 = blockIdx.y * 64;
    const int tm = (tid >> 4) << 2;   // 0..60
    const int tn = (tid & 15) << 2;   // 0..60
    float acc[4][4] = {};
    for (int k0 = 0; k0 < HD; k0 += 16) {
        int ar = r0 + (tid >> 2);
        if (ar >= M) ar = M - 1;                      // clamp (results discarded on store)
        const int lak = (tid & 3) << 2;
        float4 av = *(const float4*)(A + (size_t)ar * HD + k0 + lak);
        const int lar = tid >> 2;
        As[lak + 0][lar] = av.x; As[lak + 1][lar] = av.y;
        As[lak + 2][lar] = av.z; As[lak + 3][lar] = av.w;
        if (!transB) {
            int bk = tid >> 4;                        // 0..15
            int bn = (tid & 15) << 2;                 // 0..60
            float4 bv = *(const float4*)(B + (size_t)(k0 + bk) * HD + c0 + bn);
            Bs[bk][bn + 0] = bv.x; Bs[bk][bn + 1] = bv.y;
            Bs[bk][bn + 2] = bv.z; Bs[bk][bn + 3] = bv.w;
        } else {
            int bn = tid >> 2;                        // 0..63
            int bk = (tid & 3) << 2;                  // 0,4,8,12
            float4 bv = *(const float4*)(B + (size_t)(c0 + bn) * HD + k0 + bk);
            Bs[bk + 0][bn] = bv.x; Bs[bk + 1][bn] = bv.y;
            Bs[bk + 2][bn] = bv.z; Bs[bk + 3][bn] = bv.w;
        }
        __syncthreads();
        #pragma unroll
        for (int k = 0; k < 16; k++) {
            float a0 = As[k][tm + 0], a1 = As[k][tm + 1], a2 = As[k][tm + 2], a3 = As[k][tm + 3];
            float b0 = Bs[k][tn + 0], b1 = Bs[k][tn + 1], b2 = Bs[k][tn + 2], b3 = Bs[k][tn + 3];
            acc[0][0] += a0 * b0; acc[0][1] += a0 * b1; acc[0][2] += a0 * b2; acc[0][3] += a0 * b3;
            acc[1][0] += a1 * b0; acc[1][1] += a1 * b1; acc[1][2] += a1 * b2; acc[1][3] += a1 * b3;
            acc[2][0] += a2 * b0; acc[2][1] += a2 * b1; acc[2][2] += a2 * b2; acc[2][3] += a2 * b3;
            acc[3][0] += a3 * b0; acc[3][1] += a3 * b1; acc[3][2] += a3 * b2; acc[3][3] += a3 * b3;
        }
        __syncthreads();
    }
    #pragma unroll
    for (int i = 0; i < 4; i++) {
        int r = r0 + tm + i;
        if (r >= M) break;
        #pragma unroll
        for (int j = 0; j < 4; j++) {
            int c = c0 + tn + j;
            float v = acc[i][j];
            if (bias) v += bias[c];
            if (addb) {
                float ad = addb[(size_t)r * HD + c];
                if (mulb) ad *= mulb[(size_t)r * HD + c];
                v += ad;
            }
            C[(size_t)r * HD + c] = act_apply(v, act);
        }
    }
}

// per-edge scatter-add of src[row]*scale into out[col]; one wave per edge, float2 per lane
__global__ __launch_bounds__(256) void scatter_edges(
    const float* __restrict__ src, const int* __restrict__ row, const int* __restrict__ col,
    const float* __restrict__ dinv, float* __restrict__ out, int E)
{
    int e = blockIdx.x * 4 + threadIdx.y;
    if (e >= E) return;
    int r = row[e], c = col[e];
    float s = 1.f;
    if (dinv) s = dinv[r] * dinv[c];
    int l = threadIdx.x;  // 0..63
    float2 v = *(const float2*)(src + (size_t)r * HD + l * 2);
    atomicAdd(out + (size_t)c * HD + l * 2 + 0, v.x * s);
    atomicAdd(out + (size_t)c * HD + l * 2 + 1, v.y * s);
}

__global__ void k_deg(const int* __restrict__ row, const int* __restrict__ col,
                      float* __restrict__ deg_in, float* __restrict__ deg_out, int E) {
    int e = blockIdx.x * blockDim.x + threadIdx.x;
    if (e < E) {
        atomicAdd(&deg_in[col[e]], 1.f);
        atomicAdd(&deg_out[row[e]], 1.f);
    }
}

__global__ void k_dinv(const float* __restrict__ deg_in, float* __restrict__ dinv, int N) {
    int i = blockIdx.x * blockDim.x + threadIdx.x;
    if (i < N) dinv[i] = rsqrtf(deg_in[i] + 1.f);
}

// h = g = leaky(msum + xw*dinv^2 + b)
__global__ void k_gcn_finish(const float* __restrict__ m, const float* __restrict__ xw,
                             const float* __restrict__ dinv, const float* __restrict__ b,
                             float* __restrict__ h, float* __restrict__ g, int N) {
    int i = blockIdx.x * blockDim.x + threadIdx.x;
    if (i >= N * HD) return;
    int node = i >> 7, c = i & (HD - 1);
    float dv = dinv[node];
    float v = m[i] + xw[i] * dv * dv + b[c];
    v = v > 0.f ? v : v * NEG;
    h[i] = v;
    g[i] = v;
}

// g = (1-z)*n + z*g
__global__ void k_gru_update(const float* __restrict__ z, const float* __restrict__ n,
                             float* __restrict__ g, int N) {
    int i = blockIdx.x * blockDim.x + threadIdx.x;
    if (i >= N * HD) return;
    float zz = z[i];
    g[i] = (1.f - zz) * n[i] + zz * g[i];
}

// out = leaky(g) + h
__global__ void k_h2(const float* __restrict__ g, const float* __restrict__ h,
                     float* __restrict__ out, int N) {
    int i = blockIdx.x * blockDim.x + threadIdx.x;
    if (i >= N * HD) return;
    float v = g[i];
    v = v > 0.f ? v : v * NEG;
    out[i] = v + h[i];
}

// probs[node] = sigmoid(dot(h3[node,:], W2) + b2); one wave per node
__global__ __launch_bounds__(256) void k_head(const float* __restrict__ h3,
                                              const float* __restrict__ W2,
                                              const float* __restrict__ b2,
                                              float* __restrict__ probs, int N) {
    int node = blockIdx.x * 4 + (threadIdx.x >> 6);
    int lane = threadIdx.x & 63;
    if (node >= N) return;
    float s = h3[(size_t)node * HD + lane] * W2[lane]
            + h3[(size_t)node * HD + 64 + lane] * W2[64 + lane];
    #pragma unroll
    for (int off = 32; off > 0; off >>= 1) s += __shfl_down(s, off);
    if (lane == 0) probs[node] = 1.f / (1.f + __expf(-(s + b2[0])));
}

__global__ __launch_bounds__(256) void k_loss_node(const float* __restrict__ probs,
                                                   const float* __restrict__ deg_out,
                                                   const int* __restrict__ batch,
                                                   float* __restrict__ ed, int N) {
    __shared__ float buck[GD];
    if (threadIdx.x < GD) buck[threadIdx.x] = 0.f;
    __syncthreads();
    for (int i = blockIdx.x * blockDim.x + threadIdx.x; i < N; i += gridDim.x * blockDim.x) {
        atomicAdd(&buck[batch[i]], probs[i] * deg_out[i]);
    }
    __syncthreads();
    if (threadIdx.x < GD) atomicAdd(&ed[threadIdx.x], buck[threadIdx.x]);
}

__global__ __launch_bounds__(256) void k_loss_edge(const float* __restrict__ probs,
                                                   const int* __restrict__ row,
                                                   const int* __restrict__ col,
                                                   const int* __restrict__ batch,
                                                   float* __restrict__ ew, int E) {
    __shared__ float buck[GD];
    if (threadIdx.x < GD) buck[threadIdx.x] = 0.f;
    __syncthreads();
    for (int e = blockIdx.x * blockDim.x + threadIdx.x; e < E; e += gridDim.x * blockDim.x) {
        atomicAdd(&buck[batch[row[e]]], probs[row[e]] * probs[col[e]]);
    }
    __syncthreads();
    if (threadIdx.x < GD) atomicAdd(&ew[threadIdx.x], buck[threadIdx.x]);
}

__global__ void k_finalize(const float* __restrict__ ed, const float* __restrict__ ew,
                           float* __restrict__ out) {
    int g = threadIdx.x;
    if (g < GD) out[g] = -(ed[g] - ew[g]) * 0.5f;
}

extern "C" void kernel_launch(void* const* d_in, const int* in_sizes, int n_in,
                              void* d_out, int out_size, void* d_ws, size_t ws_size,
                              hipStream_t stream) {
    const float* x     = (const float*)d_in[0];
    const int*   ei    = (const int*)d_in[1];
    const int*   batch = (const int*)d_in[2];
    const float* W_gcn = (const float*)d_in[3];
    const float* b_gcn = (const float*)d_in[4];
    const float* W_gg  = (const float*)d_in[5];
    const float* W_ih  = (const float*)d_in[6];
    const float* W_hh  = (const float*)d_in[7];
    const float* b_ih  = (const float*)d_in[8];
    const float* b_hh  = (const float*)d_in[9];
    const float* W1    = (const float*)d_in[10];
    const float* b1    = (const float*)d_in[11];
    const float* W2    = (const float*)d_in[12];
    const float* b2    = (const float*)d_in[13];
    float* out = (float*)d_out;

    const int N = in_sizes[2];
    const int E = in_sizes[1] / 2;
    const int* row = ei;
    const int* col = ei + E;
    const size_t NH = (size_t)N * HD;

    float* F = (float*)d_ws;
    float* f_xw  = F;
    float* f_h   = F + 1 * NH;
    float* f_g   = F + 2 * NH;
    float* f_t   = F + 3 * NH;
    float* f_m   = F + 4 * NH;
    float* f_tmp = F + 5 * NH;
    float* f_r   = F + 6 * NH;
    float* f_z   = F + 7 * NH;
    float* f_degin  = F + 8 * NH;          // N
    float* f_degout = f_degin + N;         // N  (adjacent for one memset)
    float* f_dinv   = f_degout + N;        // N
    float* f_probs  = f_dinv + N;          // N
    float* f_ed     = f_probs + N;         // G
    float* f_ew     = f_ed + GD;           // G

    dim3 gemm_grid((N + 63) / 64, 2);
    dim3 sc_grid((E + 3) / 4);
    dim3 sc_block(64, 4);
    int ew_grid = (int)((NH + 255) / 256);

    // zero accumulators
    hipMemsetAsync(f_degin, 0, sizeof(float) * 2 * N, stream);
    hipMemsetAsync(f_ed, 0, sizeof(float) * 2 * GD, stream);
    hipMemsetAsync(f_m, 0, sizeof(float) * NH, stream);

    // degrees + symmetric norm
    k_deg<<<(E + 255) / 256, 256, 0, stream>>>(row, col, f_degin, f_degout, E);
    k_dinv<<<(N + 255) / 256, 256, 0, stream>>>(f_degin, f_dinv, N);

    // GCN: xw = x @ W_gcn ; aggregate ; finish
    gemm128<<<gemm_grid, 256, 0, stream>>>(x, W_gcn, nullptr, nullptr, nullptr, f_xw, N, 0, 0);
    scatter_edges<<<sc_grid, sc_block, 0, stream>>>(f_xw, row, col, f_dinv, f_m, E);
    k_gcn_finish<<<ew_grid, 256, 0, stream>>>(f_m, f_xw, f_dinv, b_gcn, f_h, f_g, N);

    // GatedGraphConv layers
    for (int l = 0; l < 3; l++) {
        gemm128<<<gemm_grid, 256, 0, stream>>>(f_g, W_gg + (size_t)l * HD * HD,
                                               nullptr, nullptr, nullptr, f_t, N, 0, 0);
        hipMemsetAsync(f_m, 0, sizeof(float) * NH, stream);
        scatter_edges<<<sc_grid, sc_block, 0, stream>>>(f_t, row, col, nullptr, f_m, E);
        // r gate
        gemm128<<<gemm_grid, 256, 0, stream>>>(f_g, W_hh + 0 * HD * HD, b_hh + 0,
                                               nullptr, nullptr, f_tmp, N, 0, 1);
        gemm128<<<gemm_grid, 256, 0, stream>>>(f_m, W_ih + 0 * HD * HD, b_ih + 0,
                                               f_tmp, nullptr, f_r, N, 2, 1);
        // z gate
        gemm128<<<gemm_grid, 256, 0, stream>>>(f_g, W_hh + 1 * HD * HD, b_hh + HD,
                                               nullptr, nullptr, f_tmp, N, 0, 1);
        gemm128<<<gemm_grid, 256, 0, stream>>>(f_m, W_ih + 1 * HD * HD, b_ih + HD,
                                               f_tmp, nullptr, f_z, N, 2, 1);
        // n gate: n = tanh(inn + r*hn)  (written over f_r)
        gemm128<<<gemm_grid, 256, 0, stream>>>(f_g, W_hh + 2 * HD * HD, b_hh + 2 * HD,
                                               nullptr, nullptr, f_tmp, N, 0, 1);
        gemm128<<<gemm_grid, 256, 0, stream>>>(f_m, W_ih + 2 * HD * HD, b_ih + 2 * HD,
                                               f_tmp, f_r, f_r, N, 3, 1);
        k_gru_update<<<ew_grid, 256, 0, stream>>>(f_z, f_r, f_g, N);
    }

    // head: h2 = leaky(g)+h ; h3 = leaky(h2@W1+b1) ; probs = sigmoid(h3@W2+b2)
    k_h2<<<ew_grid, 256, 0, stream>>>(f_g, f_h, f_m, N);
    gemm128<<<gemm_grid, 256, 0, stream>>>(f_m, W1, b1, nullptr, nullptr, f_t, N, 1, 0);
    k_head<<<(N + 3) / 4, 256, 0, stream>>>(f_t, W2, b2, f_probs, N);

    // maxcut loss
    k_loss_node<<<512, 256, 0, stream>>>(f_probs, f_degout, batch, f_ed, N);
    k_loss_edge<<<1024, 256, 0, stream>>>(f_probs, row, col, batch, f_ew, E);
    k_finalize<<<1, 64, 0, stream>>>(f_ed, f_ew, out);
}

// Round 2
// 1232.767 us; speedup vs baseline: 3.0932x; 3.0932x over previous
//
#include <hip/hip_runtime.h>
#include <math.h>

#define HD 128
#define NEG 0.01f
#define GD 64

__device__ __forceinline__ float act_apply(float v, int act) {
    if (act == 1) return v > 0.f ? v : v * NEG;          // leaky relu
    return v;
}

// C[M x 128] = act( A[M x 128] @ B[128 x 128] (+bias) )
__global__ __launch_bounds__(256) void gemm128(
    const float* __restrict__ A, const float* __restrict__ B,
    const float* __restrict__ bias, float* __restrict__ C,
    int M, int act)
{
    __shared__ float As[16][68];
    __shared__ float Bs[16][68];
    const int tid = threadIdx.x;
    const int r0 = blockIdx.x * 64;
    const int c0 = blockIdx.y * 64;
    const int tm = (tid >> 4) << 2;
    const int tn = (tid & 15) << 2;
    float acc[4][4] = {};
    for (int k0 = 0; k0 < HD; k0 += 16) {
        int ar = r0 + (tid >> 2);
        if (ar >= M) ar = M - 1;
        const int lak = (tid & 3) << 2;
        float4 av = *(const float4*)(A + (size_t)ar * HD + k0 + lak);
        const int lar = tid >> 2;
        As[lak + 0][lar] = av.x; As[lak + 1][lar] = av.y;
        As[lak + 2][lar] = av.z; As[lak + 3][lar] = av.w;
        int bk = tid >> 4;
        int bn = (tid & 15) << 2;
        float4 bv = *(const float4*)(B + (size_t)(k0 + bk) * HD + c0 + bn);
        Bs[bk][bn + 0] = bv.x; Bs[bk][bn + 1] = bv.y;
        Bs[bk][bn + 2] = bv.z; Bs[bk][bn + 3] = bv.w;
        __syncthreads();
        #pragma unroll
        for (int k = 0; k < 16; k++) {
            float a0 = As[k][tm + 0], a1 = As[k][tm + 1], a2 = As[k][tm + 2], a3 = As[k][tm + 3];
            float b0 = Bs[k][tn + 0], b1 = Bs[k][tn + 1], b2 = Bs[k][tn + 2], b3 = Bs[k][tn + 3];
            acc[0][0] += a0 * b0; acc[0][1] += a0 * b1; acc[0][2] += a0 * b2; acc[0][3] += a0 * b3;
            acc[1][0] += a1 * b0; acc[1][1] += a1 * b1; acc[1][2] += a1 * b2; acc[1][3] += a1 * b3;
            acc[2][0] += a2 * b0; acc[2][1] += a2 * b1; acc[2][2] += a2 * b2; acc[2][3] += a2 * b3;
            acc[3][0] += a3 * b0; acc[3][1] += a3 * b1; acc[3][2] += a3 * b2; acc[3][3] += a3 * b3;
        }
        __syncthreads();
    }
    #pragma unroll
    for (int i = 0; i < 4; i++) {
        int r = r0 + tm + i;
        if (r >= M) break;
        #pragma unroll
        for (int j = 0; j < 4; j++) {
            int c = c0 + tn + j;
            float v = acc[i][j];
            if (bias) v += bias[c];
            C[(size_t)r * HD + c] = act_apply(v, act);
        }
    }
}

// Fused GRU gate GEMM: G[M x 512] = [m | g] @ [W_ih | W_hh]^T with per-block K-range.
// cols 0..127: r-sum, 128..255: z-sum, 256..383: inn (m@W_ih only), 384..511: hn (g@W_hh only)
__global__ __launch_bounds__(256) void gemm_gates(
    const float* __restrict__ m, const float* __restrict__ g,
    const float* __restrict__ W_ih, const float* __restrict__ W_hh,
    const float* __restrict__ b_ih, const float* __restrict__ b_hh,
    float* __restrict__ G, int M)
{
    __shared__ float As[16][68];
    __shared__ float Bs[16][68];
    const int tid = threadIdx.x;
    const int r0 = blockIdx.x * 64;
    const int c0 = blockIdx.y * 64;   // 0..448
    const int kstart = (c0 >= 384) ? 128 : 0;
    const int kend = (c0 >= 256 && c0 < 384) ? 128 : 256;
    const int tm = (tid >> 4) << 2;
    const int tn = (tid & 15) << 2;
    float acc[4][4] = {};
    for (int k0 = kstart; k0 < kend; k0 += 16) {
        int ar = r0 + (tid >> 2);
        if (ar >= M) ar = M - 1;
        const int lak = (tid & 3) << 2;
        const int kk = k0 + lak;
        const float* Aptr = (kk < 128) ? (m + (size_t)ar * HD + kk)
                                       : (g + (size_t)ar * HD + (kk - 128));
        float4 av = *(const float4*)Aptr;
        const int lar = tid >> 2;
        As[lak + 0][lar] = av.x; As[lak + 1][lar] = av.y;
        As[lak + 2][lar] = av.z; As[lak + 3][lar] = av.w;
        int bn = tid >> 2;              // 0..63 output col in tile
        int bk = (tid & 3) << 2;        // 0,4,8,12
        int j = c0 + bn;
        int kk2 = k0 + bk;
        const float* Bptr = (kk2 < 128)
            ? (W_ih + (size_t)j * HD + kk2)
            : (W_hh + (size_t)(j < 256 ? j : j - 128) * HD + (kk2 - 128));
        float4 bv = *(const float4*)Bptr;
        Bs[bk + 0][bn] = bv.x; Bs[bk + 1][bn] = bv.y;
        Bs[bk + 2][bn] = bv.z; Bs[bk + 3][bn] = bv.w;
        __syncthreads();
        #pragma unroll
        for (int k = 0; k < 16; k++) {
            float a0 = As[k][tm + 0], a1 = As[k][tm + 1], a2 = As[k][tm + 2], a3 = As[k][tm + 3];
            float b0 = Bs[k][tn + 0], b1 = Bs[k][tn + 1], b2 = Bs[k][tn + 2], b3 = Bs[k][tn + 3];
            acc[0][0] += a0 * b0; acc[0][1] += a0 * b1; acc[0][2] += a0 * b2; acc[0][3] += a0 * b3;
            acc[1][0] += a1 * b0; acc[1][1] += a1 * b1; acc[1][2] += a1 * b2; acc[1][3] += a1 * b3;
            acc[2][0] += a2 * b0; acc[2][1] += a2 * b1; acc[2][2] += a2 * b2; acc[2][3] += a2 * b3;
            acc[3][0] += a3 * b0; acc[3][1] += a3 * b1; acc[3][2] += a3 * b2; acc[3][3] += a3 * b3;
        }
        __syncthreads();
    }
    #pragma unroll
    for (int i = 0; i < 4; i++) {
        int r = r0 + tm + i;
        if (r >= M) break;
        #pragma unroll
        for (int j = 0; j < 4; j++) {
            int c = c0 + tn + j;
            float b = (c < 256) ? (b_ih[c] + b_hh[c]) : (c < 384 ? b_ih[c] : b_hh[c - 128]);
            G[(size_t)r * 512 + c] = acc[i][j] + b;
        }
    }
}

// ---- CSR build ----
__global__ void k_hist(const int* __restrict__ row, const int* __restrict__ col,
                       int* __restrict__ cnt, int* __restrict__ degout, int E) {
    int e = blockIdx.x * blockDim.x + threadIdx.x;
    if (e < E) {
        atomicAdd(&cnt[col[e]], 1);
        atomicAdd(&degout[row[e]], 1);
    }
}

#define SCHUNK 2048
__global__ __launch_bounds__(256) void k_scan1(const int* __restrict__ cnt,
                                               int* __restrict__ excl,
                                               int* __restrict__ bsum, int N) {
    __shared__ int ts[256];
    int t = threadIdx.x;
    int base = blockIdx.x * SCHUNK + t * 8;
    int v[8]; int s = 0;
    #pragma unroll
    for (int q = 0; q < 8; q++) { int i = base + q; v[q] = (i < N) ? cnt[i] : 0; s += v[q]; }
    ts[t] = s;
    __syncthreads();
    for (int off = 1; off < 256; off <<= 1) {
        int a = (t >= off) ? ts[t - off] : 0;
        __syncthreads();
        ts[t] += a;
        __syncthreads();
    }
    int run = ts[t] - s;   // exclusive prefix of this thread's chunk
    #pragma unroll
    for (int q = 0; q < 8; q++) { int i = base + q; if (i < N) excl[i] = run; run += v[q]; }
    if (t == 255) bsum[blockIdx.x] = ts[255];
}

__global__ void k_scan2(int* bsum, int nb) {
    if (threadIdx.x == 0) {
        int run = 0;
        for (int b = 0; b < nb; b++) { int v = bsum[b]; bsum[b] = run; run += v; }
    }
}

__global__ void k_csrfin(const int* __restrict__ excl, const int* __restrict__ bsum,
                         const int* __restrict__ cnt, const int* __restrict__ degout_i,
                         int* __restrict__ offs, float* __restrict__ dinv,
                         float* __restrict__ degout_f, int N, int E) {
    int i = blockIdx.x * blockDim.x + threadIdx.x;
    if (i >= N) return;
    offs[i] = excl[i] + bsum[i >> 11];
    if (i == 0) offs[N] = E;
    dinv[i] = rsqrtf((float)cnt[i] + 1.f);
    degout_f[i] = (float)degout_i[i];
}

__global__ void k_fill(const int* __restrict__ row, const int* __restrict__ col,
                       const int* __restrict__ offs, int* __restrict__ fill,
                       int* __restrict__ csr_rows, int E) {
    int e = blockIdx.x * blockDim.x + threadIdx.x;
    if (e >= E) return;
    int c = col[e];
    int p = offs[c] + atomicAdd(&fill[c], 1);
    csr_rows[p] = row[e];
}

// ---- gather aggregation: one wave per node, register accumulate, single write ----
__global__ __launch_bounds__(256) void k_gather(
    const float* __restrict__ src, const int* __restrict__ csr,
    const int* __restrict__ offs, const float* __restrict__ dinv,
    float* __restrict__ out, int N)
{
    int node = blockIdx.x * 4 + (threadIdx.x >> 6);
    if (node >= N) return;
    int lane = threadIdx.x & 63;
    int s = offs[node], e = offs[node + 1];
    float accx = 0.f, accy = 0.f;
    int j = s;
    for (; j + 4 <= e; j += 4) {
        int r0 = csr[j], r1 = csr[j + 1], r2 = csr[j + 2], r3 = csr[j + 3];
        float2 v0 = *(const float2*)(src + (size_t)r0 * HD + lane * 2);
        float2 v1 = *(const float2*)(src + (size_t)r1 * HD + lane * 2);
        float2 v2 = *(const float2*)(src + (size_t)r2 * HD + lane * 2);
        float2 v3 = *(const float2*)(src + (size_t)r3 * HD + lane * 2);
        float s0 = dinv ? dinv[r0] : 1.f;
        float s1 = dinv ? dinv[r1] : 1.f;
        float s2 = dinv ? dinv[r2] : 1.f;
        float s3 = dinv ? dinv[r3] : 1.f;
        accx += v0.x * s0 + v1.x * s1 + v2.x * s2 + v3.x * s3;
        accy += v0.y * s0 + v1.y * s1 + v2.y * s2 + v3.y * s3;
    }
    for (; j < e; j++) {
        int r = csr[j];
        float2 v = *(const float2*)(src + (size_t)r * HD + lane * 2);
        float sc = dinv ? dinv[r] : 1.f;
        accx += v.x * sc;
        accy += v.y * sc;
    }
    float dn = dinv ? dinv[node] : 1.f;
    out[(size_t)node * HD + lane * 2 + 0] = accx * dn;
    out[(size_t)node * HD + lane * 2 + 1] = accy * dn;
}

// h = g = leaky(msum + xw*dinv^2 + b)
__global__ void k_gcn_finish(const float* __restrict__ m, const float* __restrict__ xw,
                             const float* __restrict__ dinv, const float* __restrict__ b,
                             float* __restrict__ h, float* __restrict__ g, int N) {
    int i = blockIdx.x * blockDim.x + threadIdx.x;
    if (i >= N * HD) return;
    int node = i >> 7, c = i & (HD - 1);
    float dv = dinv[node];
    float v = m[i] + xw[i] * dv * dv + b[c];
    v = v > 0.f ? v : v * NEG;
    h[i] = v;
    g[i] = v;
}

// GRU update from fused gate buffer G[N x 512]
__global__ __launch_bounds__(256) void k_gru(const float* __restrict__ G,
                                             float* __restrict__ g, int N) {
    int gid = blockIdx.x * blockDim.x + threadIdx.x;
    if (gid >= N * 32) return;
    int i = gid >> 5;
    int c4 = (gid & 31) << 2;
    const float* Gr = G + (size_t)i * 512;
    float4 rv = *(const float4*)(Gr + c4);
    float4 zv = *(const float4*)(Gr + 128 + c4);
    float4 iv = *(const float4*)(Gr + 256 + c4);
    float4 hv = *(const float4*)(Gr + 384 + c4);
    float4 gv = *(const float4*)(g + (size_t)i * HD + c4);
    float4 o;
    {
        float r = 1.f / (1.f + __expf(-rv.x));
        float z = 1.f / (1.f + __expf(-zv.x));
        float n = tanhf(iv.x + r * hv.x);
        o.x = (1.f - z) * n + z * gv.x;
    }
    {
        float r = 1.f / (1.f + __expf(-rv.y));
        float z = 1.f / (1.f + __expf(-zv.y));
        float n = tanhf(iv.y + r * hv.y);
        o.y = (1.f - z) * n + z * gv.y;
    }
    {
        float r = 1.f / (1.f + __expf(-rv.z));
        float z = 1.f / (1.f + __expf(-zv.z));
        float n = tanhf(iv.z + r * hv.z);
        o.z = (1.f - z) * n + z * gv.z;
    }
    {
        float r = 1.f / (1.f + __expf(-rv.w));
        float z = 1.f / (1.f + __expf(-zv.w));
        float n = tanhf(iv.w + r * hv.w);
        o.w = (1.f - z) * n + z * gv.w;
    }
    *(float4*)(g + (size_t)i * HD + c4) = o;
}

// out = leaky(g) + h
__global__ void k_h2(const float* __restrict__ g, const float* __restrict__ h,
                     float* __restrict__ out, int N) {
    int i = blockIdx.x * blockDim.x + threadIdx.x;
    if (i >= N * HD) return;
    float v = g[i];
    v = v > 0.f ? v : v * NEG;
    out[i] = v + h[i];
}

// probs[node] = sigmoid(dot(h3[node,:], W2) + b2)
__global__ __launch_bounds__(256) void k_head(const float* __restrict__ h3,
                                              const float* __restrict__ W2,
                                              const float* __restrict__ b2,
                                              float* __restrict__ probs, int N) {
    int node = blockIdx.x * 4 + (threadIdx.x >> 6);
    int lane = threadIdx.x & 63;
    if (node >= N) return;
    float s = h3[(size_t)node * HD + lane] * W2[lane]
            + h3[(size_t)node * HD + 64 + lane] * W2[64 + lane];
    #pragma unroll
    for (int off = 32; off > 0; off >>= 1) s += __shfl_down(s, off);
    if (lane == 0) probs[node] = 1.f / (1.f + __expf(-(s + b2[0])));
}

__global__ __launch_bounds__(256) void k_loss_node(const float* __restrict__ probs,
                                                   const float* __restrict__ deg_out,
                                                   const int* __restrict__ batch,
                                                   float* __restrict__ ed, int N) {
    __shared__ float buck[GD];
    if (threadIdx.x < GD) buck[threadIdx.x] = 0.f;
    __syncthreads();
    for (int i = blockIdx.x * blockDim.x + threadIdx.x; i < N; i += gridDim.x * blockDim.x) {
        atomicAdd(&buck[batch[i]], probs[i] * deg_out[i]);
    }
    __syncthreads();
    if (threadIdx.x < GD) atomicAdd(&ed[threadIdx.x], buck[threadIdx.x]);
}

__global__ __launch_bounds__(256) void k_loss_edge(const float* __restrict__ probs,
                                                   const int* __restrict__ row,
                                                   const int* __restrict__ col,
                                                   const int* __restrict__ batch,
                                                   float* __restrict__ ew, int E) {
    __shared__ float buck[GD];
    if (threadIdx.x < GD) buck[threadIdx.x] = 0.f;
    __syncthreads();
    for (int e = blockIdx.x * blockDim.x + threadIdx.x; e < E; e += gridDim.x * blockDim.x) {
        atomicAdd(&buck[batch[row[e]]], probs[row[e]] * probs[col[e]]);
    }
    __syncthreads();
    if (threadIdx.x < GD) atomicAdd(&ew[threadIdx.x], buck[threadIdx.x]);
}

__global__ void k_finalize(const float* __restrict__ ed, const float* __restrict__ ew,
                           float* __restrict__ out) {
    int g = threadIdx.x;
    if (g < GD) out[g] = -(ed[g] - ew[g]) * 0.5f;
}

extern "C" void kernel_launch(void* const* d_in, const int* in_sizes, int n_in,
                              void* d_out, int out_size, void* d_ws, size_t ws_size,
                              hipStream_t stream) {
    const float* x     = (const float*)d_in[0];
    const int*   ei    = (const int*)d_in[1];
    const int*   batch = (const int*)d_in[2];
    const float* W_gcn = (const float*)d_in[3];
    const float* b_gcn = (const float*)d_in[4];
    const float* W_gg  = (const float*)d_in[5];
    const float* W_ih  = (const float*)d_in[6];
    const float* W_hh  = (const float*)d_in[7];
    const float* b_ih  = (const float*)d_in[8];
    const float* b_hh  = (const float*)d_in[9];
    const float* W1    = (const float*)d_in[10];
    const float* b1    = (const float*)d_in[11];
    const float* W2    = (const float*)d_in[12];
    const float* b2    = (const float*)d_in[13];
    float* out = (float*)d_out;

    const int N = in_sizes[2];
    const int E = in_sizes[1] / 2;
    const int* row = ei;
    const int* col = ei + E;
    const size_t NH = (size_t)N * HD;

    float* F = (float*)d_ws;
    float* f_h     = F + 0 * NH;
    float* f_g     = F + 1 * NH;
    float* f_t     = F + 2 * NH;   // t / xw / h2
    float* f_a     = F + 3 * NH;   // m / h3
    float* f_gates = F + 4 * NH;   // 4 * NH
    float* f_dinv   = F + 8 * NH;
    float* f_degout = f_dinv + N;
    float* f_probs  = f_degout + N;
    float* f_ed     = f_probs + N;
    float* f_ew     = f_ed + GD;
    int* I = (int*)(f_ew + GD);
    int* i_cnt    = I;             // zeroed together (3N contiguous)
    int* i_fill   = I + N;
    int* i_degout = I + 2 * N;
    int* i_excl   = I + 3 * N;
    int* i_offs   = I + 4 * N;     // N+1
    int* i_bsum   = I + 5 * N + 8;
    int* i_csr    = I + 5 * N + 80;

    const int nb_scan = (N + SCHUNK - 1) / SCHUNK;
    dim3 gemm_grid((N + 63) / 64, 2);
    dim3 gates_grid((N + 63) / 64, 8);
    const int eg = (E + 255) / 256;
    const int ng = (N + 255) / 256;
    const int ew_grid = (int)((NH + 255) / 256);
    const int gather_grid = (N + 3) / 4;
    const int gru_grid = (N * 32 + 255) / 256;

    // zero accumulators
    hipMemsetAsync(i_cnt, 0, sizeof(int) * 3 * (size_t)N, stream);
    hipMemsetAsync(f_ed, 0, sizeof(float) * 2 * GD, stream);

    // CSR build + degrees
    k_hist<<<eg, 256, 0, stream>>>(row, col, i_cnt, i_degout, E);
    k_scan1<<<nb_scan, 256, 0, stream>>>(i_cnt, i_excl, i_bsum, N);
    k_scan2<<<1, 64, 0, stream>>>(i_bsum, nb_scan);
    k_csrfin<<<ng, 256, 0, stream>>>(i_excl, i_bsum, i_cnt, i_degout, i_offs,
                                     f_dinv, f_degout, N, E);
    k_fill<<<eg, 256, 0, stream>>>(row, col, i_offs, i_fill, i_csr, E);

    // GCN: xw = x @ W_gcn ; gather ; finish
    gemm128<<<gemm_grid, 256, 0, stream>>>(x, W_gcn, nullptr, f_t, N, 0);
    k_gather<<<gather_grid, 256, 0, stream>>>(f_t, i_csr, i_offs, f_dinv, f_a, N);
    k_gcn_finish<<<ew_grid, 256, 0, stream>>>(f_a, f_t, f_dinv, b_gcn, f_h, f_g, N);

    // GatedGraphConv layers
    for (int l = 0; l < 3; l++) {
        gemm128<<<gemm_grid, 256, 0, stream>>>(f_g, W_gg + (size_t)l * HD * HD,
                                               nullptr, f_t, N, 0);
        k_gather<<<gather_grid, 256, 0, stream>>>(f_t, i_csr, i_offs, nullptr, f_a, N);
        gemm_gates<<<gates_grid, 256, 0, stream>>>(f_a, f_g, W_ih, W_hh, b_ih, b_hh,
                                                   f_gates, N);
        k_gru<<<gru_grid, 256, 0, stream>>>(f_gates, f_g, N);
    }

    // head
    k_h2<<<ew_grid, 256, 0, stream>>>(f_g, f_h, f_t, N);
    gemm128<<<gemm_grid, 256, 0, stream>>>(f_t, W1, b1, f_a, N, 1);
    k_head<<<(N + 3) / 4, 256, 0, stream>>>(f_a, W2, b2, f_probs, N);

    // maxcut loss
    k_loss_node<<<512, 256, 0, stream>>>(f_probs, f_degout, batch, f_ed, N);
    k_loss_edge<<<1024, 256, 0, stream>>>(f_probs, row, col, batch, f_ew, E);
    k_finalize<<<1, 64, 0, stream>>>(f_ed, f_ew, out);
}

// Round 3
// 912.247 us; speedup vs baseline: 4.1800x; 1.3514x over previous
//
#include <hip/hip_runtime.h>
#include <math.h>

#define HD 128
#define NEG 0.01f
#define GD 64
#define LDST 136   // LDS row stride in ushorts (128 + 8 pad -> 2-way-free bank pattern)

typedef short bf16x8 __attribute__((ext_vector_type(8)));
typedef float floatx4 __attribute__((ext_vector_type(4)));

__device__ __forceinline__ unsigned short f2bf(float f) {
    unsigned int u = __float_as_uint(f);
    u += 0x7fffu + ((u >> 16) & 1u);   // RNE
    return (unsigned short)(u >> 16);
}
__device__ __forceinline__ float bf2f(unsigned short b) {
    return __uint_as_float(((unsigned int)b) << 16);
}

// ---- MFMA GEMM: C[M x Nc] = act( A_bf[M x 128] @ BT_bf[Nc x 128]^T + bias ) ----
// BT is row-major [n][k]. Tile 128x128, 256 threads (4 waves), K=128 single pass.
__global__ __launch_bounds__(256) void gemm_mfma(
    const unsigned short* __restrict__ A, const unsigned short* __restrict__ BT,
    const float* __restrict__ bias, float* __restrict__ C32,
    unsigned short* __restrict__ C16, int M, int ldC, int act)
{
    __shared__ unsigned short As[128 * LDST];
    __shared__ unsigned short Bs[128 * LDST];
    const int tid = threadIdx.x;
    const int r0 = blockIdx.x * 128;
    const int n0 = blockIdx.y * 128;
    {   // stage A,B tiles: thread t -> row t>>1, half t&1 (128B contiguous each)
        int rowi = tid >> 1, half = tid & 1;
        int gr = r0 + rowi; if (gr >= M) gr = M - 1;
        const float4* sa = (const float4*)(A + (size_t)gr * HD + half * 64);
        float4* da = (float4*)(As + rowi * LDST + half * 64);
        const float4* sb = (const float4*)(BT + (size_t)(n0 + rowi) * HD + half * 64);
        float4* db = (float4*)(Bs + rowi * LDST + half * 64);
        #pragma unroll
        for (int i = 0; i < 8; i++) { da[i] = sa[i]; db[i] = sb[i]; }
    }
    __syncthreads();

    const int wave = tid >> 6;
    const int lane = tid & 63;
    const int m16 = lane & 15;
    const int quad = lane >> 4;

    floatx4 acc[2][8];
    #pragma unroll
    for (int i = 0; i < 2; i++)
        #pragma unroll
        for (int j = 0; j < 8; j++) acc[i][j] = (floatx4){0.f, 0.f, 0.f, 0.f};

    const unsigned short* ar0 = As + (wave * 32 + m16) * LDST;
    const unsigned short* ar1 = As + (wave * 32 + 16 + m16) * LDST;
    #pragma unroll
    for (int ks = 0; ks < 4; ks++) {
        const int koff = ks * 32 + quad * 8;
        bf16x8 a0 = *(const bf16x8*)(ar0 + koff);
        bf16x8 a1 = *(const bf16x8*)(ar1 + koff);
        #pragma unroll
        for (int cg = 0; cg < 8; cg++) {
            bf16x8 b = *(const bf16x8*)(Bs + (cg * 16 + m16) * LDST + koff);
            acc[0][cg] = __builtin_amdgcn_mfma_f32_16x16x32_bf16(a0, b, acc[0][cg], 0, 0, 0);
            acc[1][cg] = __builtin_amdgcn_mfma_f32_16x16x32_bf16(a1, b, acc[1][cg], 0, 0, 0);
        }
    }

    #pragma unroll
    for (int rg = 0; rg < 2; rg++) {
        #pragma unroll
        for (int cg = 0; cg < 8; cg++) {
            #pragma unroll
            for (int i = 0; i < 4; i++) {
                int r = r0 + wave * 32 + rg * 16 + quad * 4 + i;
                if (r >= M) continue;
                int c = n0 + cg * 16 + m16;
                float v = acc[rg][cg][i];
                if (bias) v += bias[c];
                if (act == 1) v = v > 0.f ? v : v * NEG;
                if (C32) C32[(size_t)r * ldC + c] = v;
                if (C16) C16[(size_t)r * ldC + c] = f2bf(v);
            }
        }
    }
}

// ---- weight prep ----
__global__ void k_cast(const float* __restrict__ s, unsigned short* __restrict__ d, int n) {
    int i = blockIdx.x * blockDim.x + threadIdx.x;
    if (i < n) d[i] = f2bf(s[i]);
}
// src [R][C] -> dst [C][R] bf16  (dst[n*R+k] = src[k*C+n])
__global__ void k_castT(const float* __restrict__ s, unsigned short* __restrict__ d, int R, int C) {
    int i = blockIdx.x * blockDim.x + threadIdx.x;
    if (i >= R * C) return;
    int n = i / R, k = i - n * R;
    d[i] = f2bf(s[(size_t)k * C + n]);
}

// ---- CSR build ----
__global__ void k_hist(const int* __restrict__ row, const int* __restrict__ col,
                       int* __restrict__ cnt, int* __restrict__ degout, int E) {
    int e = blockIdx.x * blockDim.x + threadIdx.x;
    if (e < E) {
        atomicAdd(&cnt[col[e]], 1);
        atomicAdd(&degout[row[e]], 1);
    }
}

#define SCHUNK 2048
__global__ __launch_bounds__(256) void k_scan1(const int* __restrict__ cnt,
                                               int* __restrict__ excl,
                                               int* __restrict__ bsum, int N) {
    __shared__ int ts[256];
    int t = threadIdx.x;
    int base = blockIdx.x * SCHUNK + t * 8;
    int v[8]; int s = 0;
    #pragma unroll
    for (int q = 0; q < 8; q++) { int i = base + q; v[q] = (i < N) ? cnt[i] : 0; s += v[q]; }
    ts[t] = s;
    __syncthreads();
    for (int off = 1; off < 256; off <<= 1) {
        int a = (t >= off) ? ts[t - off] : 0;
        __syncthreads();
        ts[t] += a;
        __syncthreads();
    }
    int run = ts[t] - s;
    #pragma unroll
    for (int q = 0; q < 8; q++) { int i = base + q; if (i < N) excl[i] = run; run += v[q]; }
    if (t == 255) bsum[blockIdx.x] = ts[255];
}

__global__ void k_scan2(int* bsum, int nb) {
    if (threadIdx.x == 0) {
        int run = 0;
        for (int b = 0; b < nb; b++) { int v = bsum[b]; bsum[b] = run; run += v; }
    }
}

__global__ void k_csrfin(const int* __restrict__ excl, const int* __restrict__ bsum,
                         const int* __restrict__ cnt, const int* __restrict__ degout_i,
                         int* __restrict__ offs, float* __restrict__ dinv,
                         float* __restrict__ degout_f, int N, int E) {
    int i = blockIdx.x * blockDim.x + threadIdx.x;
    if (i >= N) return;
    offs[i] = excl[i] + bsum[i >> 11];
    if (i == 0) offs[N] = E;
    dinv[i] = rsqrtf((float)cnt[i] + 1.f);
    degout_f[i] = (float)degout_i[i];
}

__global__ void k_fill(const int* __restrict__ row, const int* __restrict__ col,
                       const int* __restrict__ offs, int* __restrict__ fill,
                       int* __restrict__ csr_rows, int E) {
    int e = blockIdx.x * blockDim.x + threadIdx.x;
    if (e >= E) return;
    int c = col[e];
    int p = offs[c] + atomicAdd(&fill[c], 1);
    csr_rows[p] = row[e];
}

// ---- gather aggregation over bf16 src; one wave per node ----
__global__ __launch_bounds__(256) void k_gather_bf(
    const unsigned short* __restrict__ src, const int* __restrict__ csr,
    const int* __restrict__ offs, const float* __restrict__ dinv,
    float* __restrict__ out32, unsigned short* __restrict__ out16, int N)
{
    int node = blockIdx.x * 4 + (threadIdx.x >> 6);
    if (node >= N) return;
    int lane = threadIdx.x & 63;
    int s = offs[node], e = offs[node + 1];
    float ax = 0.f, ay = 0.f;
    int j = s;
    for (; j + 4 <= e; j += 4) {
        int r0 = csr[j], r1 = csr[j + 1], r2 = csr[j + 2], r3 = csr[j + 3];
        unsigned int u0 = *(const unsigned int*)(src + (size_t)r0 * HD + lane * 2);
        unsigned int u1 = *(const unsigned int*)(src + (size_t)r1 * HD + lane * 2);
        unsigned int u2 = *(const unsigned int*)(src + (size_t)r2 * HD + lane * 2);
        unsigned int u3 = *(const unsigned int*)(src + (size_t)r3 * HD + lane * 2);
        float s0 = dinv ? dinv[r0] : 1.f;
        float s1 = dinv ? dinv[r1] : 1.f;
        float s2 = dinv ? dinv[r2] : 1.f;
        float s3 = dinv ? dinv[r3] : 1.f;
        ax += __uint_as_float(u0 << 16) * s0 + __uint_as_float(u1 << 16) * s1
            + __uint_as_float(u2 << 16) * s2 + __uint_as_float(u3 << 16) * s3;
        ay += __uint_as_float(u0 & 0xffff0000u) * s0 + __uint_as_float(u1 & 0xffff0000u) * s1
            + __uint_as_float(u2 & 0xffff0000u) * s2 + __uint_as_float(u3 & 0xffff0000u) * s3;
    }
    for (; j < e; j++) {
        int r = csr[j];
        unsigned int u = *(const unsigned int*)(src + (size_t)r * HD + lane * 2);
        float sc = dinv ? dinv[r] : 1.f;
        ax += __uint_as_float(u << 16) * sc;
        ay += __uint_as_float(u & 0xffff0000u) * sc;
    }
    float dn = dinv ? dinv[node] : 1.f;
    ax *= dn; ay *= dn;
    if (out32) {
        out32[(size_t)node * HD + lane * 2 + 0] = ax;
        out32[(size_t)node * HD + lane * 2 + 1] = ay;
    }
    if (out16) {
        unsigned int p = (unsigned int)f2bf(ax) | ((unsigned int)f2bf(ay) << 16);
        *(unsigned int*)(out16 + (size_t)node * HD + lane * 2) = p;
    }
}

// h = g = leaky(m + xw*dinv^2 + b); writes fp32 h, fp32 g, bf16 g
__global__ void k_gcn_finish(const float* __restrict__ m, const float* __restrict__ xw,
                             const float* __restrict__ dinv, const float* __restrict__ b,
                             float* __restrict__ h, float* __restrict__ g,
                             unsigned short* __restrict__ g16, int N) {
    int gid = blockIdx.x * blockDim.x + threadIdx.x;
    if (gid >= N * 64) return;
    int node = gid >> 6, c2 = (gid & 63) * 2;
    size_t i = (size_t)node * HD + c2;
    float dv = dinv[node]; dv *= dv;
    float v0 = m[i] + xw[i] * dv + b[c2];
    float v1 = m[i + 1] + xw[i + 1] * dv + b[c2 + 1];
    v0 = v0 > 0.f ? v0 : v0 * NEG;
    v1 = v1 > 0.f ? v1 : v1 * NEG;
    h[i] = v0; h[i + 1] = v1;
    g[i] = v0; g[i + 1] = v1;
    *(unsigned int*)(g16 + i) = (unsigned int)f2bf(v0) | ((unsigned int)f2bf(v1) << 16);
}

// GRU update from bf16 gi[N x 384], gh[N x 384]; fp32 state g; writes g fp32 + bf16
__global__ __launch_bounds__(256) void k_gru(const unsigned short* __restrict__ gi16,
                                             const unsigned short* __restrict__ gh16,
                                             float* __restrict__ g,
                                             unsigned short* __restrict__ g16, int N) {
    int gid = blockIdx.x * blockDim.x + threadIdx.x;
    if (gid >= N * 32) return;
    int i = gid >> 5;
    int c = (gid & 31) * 4;
    const unsigned short* gi = gi16 + (size_t)i * 384;
    const unsigned short* gh = gh16 + (size_t)i * 384;
    ushort4 irv = *(const ushort4*)(gi + c);
    ushort4 izv = *(const ushort4*)(gi + 128 + c);
    ushort4 inv = *(const ushort4*)(gi + 256 + c);
    ushort4 hrv = *(const ushort4*)(gh + c);
    ushort4 hzv = *(const ushort4*)(gh + 128 + c);
    ushort4 hnv = *(const ushort4*)(gh + 256 + c);
    float4 gv = *(const float4*)(g + (size_t)i * HD + c);
    float4 o;
    float r, z, n;
    r = 1.f / (1.f + __expf(-(bf2f(irv.x) + bf2f(hrv.x))));
    z = 1.f / (1.f + __expf(-(bf2f(izv.x) + bf2f(hzv.x))));
    n = tanhf(bf2f(inv.x) + r * bf2f(hnv.x));
    o.x = (1.f - z) * n + z * gv.x;
    r = 1.f / (1.f + __expf(-(bf2f(irv.y) + bf2f(hrv.y))));
    z = 1.f / (1.f + __expf(-(bf2f(izv.y) + bf2f(hzv.y))));
    n = tanhf(bf2f(inv.y) + r * bf2f(hnv.y));
    o.y = (1.f - z) * n + z * gv.y;
    r = 1.f / (1.f + __expf(-(bf2f(irv.z) + bf2f(hrv.z))));
    z = 1.f / (1.f + __expf(-(bf2f(izv.z) + bf2f(hzv.z))));
    n = tanhf(bf2f(inv.z) + r * bf2f(hnv.z));
    o.z = (1.f - z) * n + z * gv.z;
    r = 1.f / (1.f + __expf(-(bf2f(irv.w) + bf2f(hrv.w))));
    z = 1.f / (1.f + __expf(-(bf2f(izv.w) + bf2f(hzv.w))));
    n = tanhf(bf2f(inv.w) + r * bf2f(hnv.w));
    o.w = (1.f - z) * n + z * gv.w;
    *(float4*)(g + (size_t)i * HD + c) = o;
    ushort4 ob;
    ob.x = f2bf(o.x); ob.y = f2bf(o.y); ob.z = f2bf(o.z); ob.w = f2bf(o.w);
    *(ushort4*)(g16 + (size_t)i * HD + c) = ob;
}

// t_bf = bf16( leaky(g) + h )
__global__ void k_h2(const float* __restrict__ g, const float* __restrict__ h,
                     unsigned short* __restrict__ out16, int N) {
    int gid = blockIdx.x * blockDim.x + threadIdx.x;
    if (gid >= N * 32) return;
    size_t i = (size_t)gid * 4;
    float4 gv = *(const float4*)(g + i);
    float4 hv = *(const float4*)(h + i);
    ushort4 o;
    float v;
    v = gv.x > 0.f ? gv.x : gv.x * NEG; o.x = f2bf(v + hv.x);
    v = gv.y > 0.f ? gv.y : gv.y * NEG; o.y = f2bf(v + hv.y);
    v = gv.z > 0.f ? gv.z : gv.z * NEG; o.z = f2bf(v + hv.z);
    v = gv.w > 0.f ? gv.w : gv.w * NEG; o.w = f2bf(v + hv.w);
    *(ushort4*)(out16 + i) = o;
}

// probs[node] = sigmoid(dot(h3_bf[node,:], W2) + b2)
__global__ __launch_bounds__(256) void k_head(const unsigned short* __restrict__ h3,
                                              const float* __restrict__ W2,
                                              const float* __restrict__ b2,
                                              float* __restrict__ probs, int N) {
    int node = blockIdx.x * 4 + (threadIdx.x >> 6);
    int lane = threadIdx.x & 63;
    if (node >= N) return;
    float s = bf2f(h3[(size_t)node * HD + lane]) * W2[lane]
            + bf2f(h3[(size_t)node * HD + 64 + lane]) * W2[64 + lane];
    #pragma unroll
    for (int off = 32; off > 0; off >>= 1) s += __shfl_down(s, off);
    if (lane == 0) probs[node] = 1.f / (1.f + __expf(-(s + b2[0])));
}

__global__ __launch_bounds__(256) void k_loss_node(const float* __restrict__ probs,
                                                   const float* __restrict__ deg_out,
                                                   const int* __restrict__ batch,
                                                   float* __restrict__ ed, int N) {
    __shared__ float buck[GD];
    if (threadIdx.x < GD) buck[threadIdx.x] = 0.f;
    __syncthreads();
    for (int i = blockIdx.x * blockDim.x + threadIdx.x; i < N; i += gridDim.x * blockDim.x) {
        atomicAdd(&buck[batch[i]], probs[i] * deg_out[i]);
    }
    __syncthreads();
    if (threadIdx.x < GD) atomicAdd(&ed[threadIdx.x], buck[threadIdx.x]);
}

__global__ __launch_bounds__(256) void k_loss_edge(const float* __restrict__ probs,
                                                   const int* __restrict__ row,
                                                   const int* __restrict__ col,
                                                   const int* __restrict__ batch,
                                                   float* __restrict__ ew, int E) {
    __shared__ float buck[GD];
    if (threadIdx.x < GD) buck[threadIdx.x] = 0.f;
    __syncthreads();
    for (int e = blockIdx.x * blockDim.x + threadIdx.x; e < E; e += gridDim.x * blockDim.x) {
        atomicAdd(&buck[batch[row[e]]], probs[row[e]] * probs[col[e]]);
    }
    __syncthreads();
    if (threadIdx.x < GD) atomicAdd(&ew[threadIdx.x], buck[threadIdx.x]);
}

__global__ void k_finalize(const float* __restrict__ ed, const float* __restrict__ ew,
                           float* __restrict__ out) {
    int g = threadIdx.x;
    if (g < GD) out[g] = -(ed[g] - ew[g]) * 0.5f;
}

extern "C" void kernel_launch(void* const* d_in, const int* in_sizes, int n_in,
                              void* d_out, int out_size, void* d_ws, size_t ws_size,
                              hipStream_t stream) {
    const float* x     = (const float*)d_in[0];
    const int*   ei    = (const int*)d_in[1];
    const int*   batch = (const int*)d_in[2];
    const float* W_gcn = (const float*)d_in[3];
    const float* b_gcn = (const float*)d_in[4];
    const float* W_gg  = (const float*)d_in[5];
    const float* W_ih  = (const float*)d_in[6];
    const float* W_hh  = (const float*)d_in[7];
    const float* b_ih  = (const float*)d_in[8];
    const float* b_hh  = (const float*)d_in[9];
    const float* W1    = (const float*)d_in[10];
    const float* b1    = (const float*)d_in[11];
    const float* W2    = (const float*)d_in[12];
    const float* b2    = (const float*)d_in[13];
    float* out = (float*)d_out;

    const int N = in_sizes[2];
    const int E = in_sizes[1] / 2;
    const int* row = ei;
    const int* col = ei + E;
    const size_t NH = (size_t)N * HD;

    float* F = (float*)d_ws;
    float* f_h  = F + 0 * NH;
    float* f_g  = F + 1 * NH;
    float* f_xw = F + 2 * NH;
    float* f_a  = F + 3 * NH;
    unsigned short* U = (unsigned short*)(F + 4 * NH);
    unsigned short* x_bf = U;                 // aliased: h3 bf16 at the end
    unsigned short* a16  = U;
    unsigned short* g_bf = U + 1 * NH;
    unsigned short* t_bf = U + 2 * NH;
    unsigned short* m_bf = U + 3 * NH;
    unsigned short* gi16 = U + 4 * NH;        // N x 384
    unsigned short* gh16 = U + 7 * NH;        // N x 384
    unsigned short* Wq   = U + 10 * NH;
    unsigned short* WgcnT = Wq;               // 128*128
    unsigned short* WggT  = Wq + 16384;       // 3*128*128
    unsigned short* Wih16 = Wq + 4 * 16384;   // 384*128
    unsigned short* Whh16 = Wih16 + 49152;
    unsigned short* W1T   = Whh16 + 49152;
    float* S = (float*)(Wq + 180224);
    float* f_dinv   = S;
    float* f_degout = S + N;
    float* f_probs  = S + 2 * N;
    float* f_ed     = S + 3 * N;
    float* f_ew     = f_ed + GD;
    int* I = (int*)(f_ew + GD);
    int* i_cnt    = I;
    int* i_fill   = I + N;
    int* i_degout = I + 2 * N;
    int* i_excl   = I + 3 * N;
    int* i_offs   = I + 4 * N;     // N+1
    int* i_bsum   = I + 5 * N + 8;
    int* i_csr    = I + 5 * N + 80;

    const int nb_scan = (N + SCHUNK - 1) / SCHUNK;
    dim3 g1((N + 127) / 128, 1);   // Nc=128 gemm
    dim3 g3((N + 127) / 128, 3);   // Nc=384 gemm
    const int eg = (E + 255) / 256;
    const int ng = (N + 255) / 256;
    const int gather_grid = (N + 3) / 4;
    const int g32 = (N * 32 + 255) / 256;
    const int g64 = (N * 64 + 255) / 256;

    hipMemsetAsync(i_cnt, 0, sizeof(int) * 3 * (size_t)N, stream);
    hipMemsetAsync(f_ed, 0, sizeof(float) * 2 * GD, stream);

    // weight prep (bf16, [n][k] layout)
    k_castT<<<64, 256, 0, stream>>>(W_gcn, WgcnT, 128, 128);
    for (int l = 0; l < 3; l++)
        k_castT<<<64, 256, 0, stream>>>(W_gg + (size_t)l * 16384, WggT + (size_t)l * 16384, 128, 128);
    k_cast<<<192, 256, 0, stream>>>(W_ih, Wih16, 49152);
    k_cast<<<192, 256, 0, stream>>>(W_hh, Whh16, 49152);
    k_castT<<<64, 256, 0, stream>>>(W1, W1T, 128, 128);
    k_cast<<<(int)((NH + 255) / 256), 256, 0, stream>>>(x, x_bf, (int)NH);

    // CSR build + degrees
    k_hist<<<eg, 256, 0, stream>>>(row, col, i_cnt, i_degout, E);
    k_scan1<<<nb_scan, 256, 0, stream>>>(i_cnt, i_excl, i_bsum, N);
    k_scan2<<<1, 64, 0, stream>>>(i_bsum, nb_scan);
    k_csrfin<<<ng, 256, 0, stream>>>(i_excl, i_bsum, i_cnt, i_degout, i_offs,
                                     f_dinv, f_degout, N, E);
    k_fill<<<eg, 256, 0, stream>>>(row, col, i_offs, i_fill, i_csr, E);

    // GCN: xw (fp32 + bf16) ; gather (fp32 out) ; finish
    gemm_mfma<<<g1, 256, 0, stream>>>(x_bf, WgcnT, nullptr, f_xw, t_bf, N, HD, 0);
    k_gather_bf<<<gather_grid, 256, 0, stream>>>(t_bf, i_csr, i_offs, f_dinv, f_a, nullptr, N);
    k_gcn_finish<<<g64, 256, 0, stream>>>(f_a, f_xw, f_dinv, b_gcn, f_h, f_g, g_bf, N);

    // GatedGraphConv layers
    for (int l = 0; l < 3; l++) {
        gemm_mfma<<<g1, 256, 0, stream>>>(g_bf, WggT + (size_t)l * 16384, nullptr,
                                          nullptr, t_bf, N, HD, 0);
        k_gather_bf<<<gather_grid, 256, 0, stream>>>(t_bf, i_csr, i_offs, nullptr,
                                                     nullptr, m_bf, N);
        gemm_mfma<<<g3, 256, 0, stream>>>(m_bf, Wih16, b_ih, nullptr, gi16, N, 384, 0);
        gemm_mfma<<<g3, 256, 0, stream>>>(g_bf, Whh16, b_hh, nullptr, gh16, N, 384, 0);
        k_gru<<<g32, 256, 0, stream>>>(gi16, gh16, f_g, g_bf, N);
    }

    // head
    k_h2<<<g32, 256, 0, stream>>>(f_g, f_h, t_bf, N);
    gemm_mfma<<<g1, 256, 0, stream>>>(t_bf, W1T, b1, nullptr, a16, N, HD, 1);
    k_head<<<(N + 3) / 4, 256, 0, stream>>>(a16, W2, b2, f_probs, N);

    // maxcut loss
    k_loss_node<<<512, 256, 0, stream>>>(f_probs, f_degout, batch, f_ed, N);
    k_loss_edge<<<1024, 256, 0, stream>>>(f_probs, row, col, batch, f_ew, E);
    k_finalize<<<1, 64, 0, stream>>>(f_ed, f_ew, out);
}

// Round 4
// 776.900 us; speedup vs baseline: 4.9082x; 1.1742x over previous
//
#include <hip/hip_runtime.h>
#include <math.h>

#define HD 128
#define NEG 0.01f
#define GD 64
#define LDST 136   // LDS row stride in ushorts

typedef short bf16x8 __attribute__((ext_vector_type(8)));
typedef float floatx4 __attribute__((ext_vector_type(4)));

__device__ __forceinline__ unsigned short f2bf(float f) {
    unsigned int u = __float_as_uint(f);
    u += 0x7fffu + ((u >> 16) & 1u);   // RNE
    return (unsigned short)(u >> 16);
}
__device__ __forceinline__ float bf2f(unsigned short b) {
    return __uint_as_float(((unsigned int)b) << 16);
}
__device__ __forceinline__ float sigm(float v) { return 1.f / (1.f + __expf(-v)); }

// 128x128 K=128 MFMA partial product: A rows from LDS, B ([n][k] bf16) from global (L2-hot)
__device__ __forceinline__ void mm128(const unsigned short* __restrict__ a0p,
                                      const unsigned short* __restrict__ a1p,
                                      const unsigned short* __restrict__ W,
                                      int m16, int quad, floatx4 acc[2][8]) {
    #pragma unroll
    for (int ks = 0; ks < 4; ks++) {
        const int koff = ks * 32 + quad * 8;
        bf16x8 a0 = *(const bf16x8*)(a0p + koff);
        bf16x8 a1 = *(const bf16x8*)(a1p + koff);
        #pragma unroll
        for (int cg = 0; cg < 8; cg++) {
            bf16x8 b = *(const bf16x8*)(W + (size_t)(cg * 16 + m16) * HD + koff);
            acc[0][cg] = __builtin_amdgcn_mfma_f32_16x16x32_bf16(a0, b, acc[0][cg], 0, 0, 0);
            acc[1][cg] = __builtin_amdgcn_mfma_f32_16x16x32_bf16(a1, b, acc[1][cg], 0, 0, 0);
        }
    }
}

// ---- plain MFMA GEMM (GCN proj + W_gg msg proj): C = A_bf @ BT_bf^T ----
__global__ __launch_bounds__(256) void gemm_mfma(
    const unsigned short* __restrict__ A, const unsigned short* __restrict__ BT,
    float* __restrict__ C32, unsigned short* __restrict__ C16, int M)
{
    __shared__ unsigned short As[128 * LDST];
    __shared__ unsigned short Bs[128 * LDST];
    const int tid = threadIdx.x;
    const int r0 = blockIdx.x * 128;
    {
        int rowi = tid >> 1, half = tid & 1;
        int gr = r0 + rowi; if (gr >= M) gr = M - 1;
        const float4* sa = (const float4*)(A + (size_t)gr * HD + half * 64);
        float4* da = (float4*)(As + rowi * LDST + half * 64);
        const float4* sb = (const float4*)(BT + (size_t)rowi * HD + half * 64);
        float4* db = (float4*)(Bs + rowi * LDST + half * 64);
        #pragma unroll
        for (int i = 0; i < 8; i++) { da[i] = sa[i]; db[i] = sb[i]; }
    }
    __syncthreads();
    const int wave = tid >> 6, lane = tid & 63;
    const int m16 = lane & 15, quad = lane >> 4;
    floatx4 acc[2][8];
    #pragma unroll
    for (int i = 0; i < 2; i++)
        #pragma unroll
        for (int j = 0; j < 8; j++) acc[i][j] = (floatx4){0.f, 0.f, 0.f, 0.f};
    const unsigned short* ar0 = As + (wave * 32 + m16) * LDST;
    const unsigned short* ar1 = As + (wave * 32 + 16 + m16) * LDST;
    #pragma unroll
    for (int ks = 0; ks < 4; ks++) {
        const int koff = ks * 32 + quad * 8;
        bf16x8 a0 = *(const bf16x8*)(ar0 + koff);
        bf16x8 a1 = *(const bf16x8*)(ar1 + koff);
        #pragma unroll
        for (int cg = 0; cg < 8; cg++) {
            bf16x8 b = *(const bf16x8*)(Bs + (cg * 16 + m16) * LDST + koff);
            acc[0][cg] = __builtin_amdgcn_mfma_f32_16x16x32_bf16(a0, b, acc[0][cg], 0, 0, 0);
            acc[1][cg] = __builtin_amdgcn_mfma_f32_16x16x32_bf16(a1, b, acc[1][cg], 0, 0, 0);
        }
    }
    #pragma unroll
    for (int rg = 0; rg < 2; rg++)
        #pragma unroll
        for (int cg = 0; cg < 8; cg++)
            #pragma unroll
            for (int i = 0; i < 4; i++) {
                int r = r0 + wave * 32 + rg * 16 + quad * 4 + i;
                if (r >= M) continue;
                int c = cg * 16 + m16;
                float v = acc[rg][cg][i];
                if (C32) C32[(size_t)r * HD + c] = v;
                C16[(size_t)r * HD + c] = f2bf(v);
            }
}

// ---- fused GRU layer: gates GEMMs + GRU update, no gate materialization ----
__global__ __launch_bounds__(256) void k_gru_fused(
    const unsigned short* __restrict__ m_bf, const unsigned short* __restrict__ g_bf,
    const unsigned short* __restrict__ Wih, const unsigned short* __restrict__ Whh,
    const float* __restrict__ b_ih, const float* __restrict__ b_hh,
    const float* __restrict__ g_in, float* __restrict__ g_out,
    unsigned short* __restrict__ g16_out, int M)
{
    __shared__ unsigned short Am[128 * LDST];
    __shared__ unsigned short Ag[128 * LDST];
    const int tid = threadIdx.x;
    const int r0 = blockIdx.x * 128;
    {
        int rowi = tid >> 1, half = tid & 1;
        int gr = r0 + rowi; if (gr >= M) gr = M - 1;
        const float4* sm = (const float4*)(m_bf + (size_t)gr * HD + half * 64);
        const float4* sg = (const float4*)(g_bf + (size_t)gr * HD + half * 64);
        float4* dm = (float4*)(Am + rowi * LDST + half * 64);
        float4* dg = (float4*)(Ag + rowi * LDST + half * 64);
        #pragma unroll
        for (int i = 0; i < 8; i++) { dm[i] = sm[i]; dg[i] = sg[i]; }
    }
    __syncthreads();
    const int wave = tid >> 6, lane = tid & 63;
    const int m16 = lane & 15, quad = lane >> 4;
    const unsigned short* am0 = Am + (wave * 32 + m16) * LDST;
    const unsigned short* am1 = Am + (wave * 32 + 16 + m16) * LDST;
    const unsigned short* ag0 = Ag + (wave * 32 + m16) * LDST;
    const unsigned short* ag1 = Ag + (wave * 32 + 16 + m16) * LDST;

    floatx4 accR[2][8], accH[2][8];
    #pragma unroll
    for (int i = 0; i < 2; i++)
        #pragma unroll
        for (int j = 0; j < 8; j++) {
            accR[i][j] = (floatx4){0.f, 0.f, 0.f, 0.f};
            accH[i][j] = (floatx4){0.f, 0.f, 0.f, 0.f};
        }
    // r-gate pre-activation: m@W_ih_r + g@W_hh_r
    mm128(am0, am1, Wih, m16, quad, accR);
    mm128(ag0, ag1, Whh, m16, quad, accR);
    // hn: g@W_hh_n
    mm128(ag0, ag1, Whh + 256 * HD, m16, quad, accH);
    // fold: accH = sigmoid(r)*(hn + b_hhn)
    #pragma unroll
    for (int rg = 0; rg < 2; rg++)
        #pragma unroll
        for (int cg = 0; cg < 8; cg++) {
            int c = cg * 16 + m16;
            float br = b_ih[c] + b_hh[c];
            float bhn = b_hh[256 + c];
            #pragma unroll
            for (int i = 0; i < 4; i++) {
                float r = sigm(accR[rg][cg][i] + br);
                accH[rg][cg][i] = r * (accH[rg][cg][i] + bhn);
            }
        }
    // accH += m@W_ih_n   (n pre-activation minus b_ihn)
    mm128(am0, am1, Wih + 256 * HD, m16, quad, accH);
    // z-gate (reuse accR registers)
    floatx4 accZ[2][8];
    #pragma unroll
    for (int i = 0; i < 2; i++)
        #pragma unroll
        for (int j = 0; j < 8; j++) accZ[i][j] = (floatx4){0.f, 0.f, 0.f, 0.f};
    mm128(am0, am1, Wih + 128 * HD, m16, quad, accZ);
    mm128(ag0, ag1, Whh + 128 * HD, m16, quad, accZ);
    // epilogue
    #pragma unroll
    for (int rg = 0; rg < 2; rg++)
        #pragma unroll
        for (int cg = 0; cg < 8; cg++) {
            int c = cg * 16 + m16;
            float bz = b_ih[128 + c] + b_hh[128 + c];
            float bin = b_ih[256 + c];
            #pragma unroll
            for (int i = 0; i < 4; i++) {
                int r = r0 + wave * 32 + rg * 16 + quad * 4 + i;
                if (r >= M) continue;
                float z = sigm(accZ[rg][cg][i] + bz);
                float n = tanhf(accH[rg][cg][i] + bin);
                float gv = g_in[(size_t)r * HD + c];
                float o = (1.f - z) * n + z * gv;
                g_out[(size_t)r * HD + c] = o;
                g16_out[(size_t)r * HD + c] = f2bf(o);
            }
        }
}

// ---- fused head: h2 = leaky(g)+h ; h3 = leaky(h2@W1+b1) ; probs = sigmoid(h3.W2+b2) ----
__global__ __launch_bounds__(256) void k_head_fused(
    const float* __restrict__ g, const float* __restrict__ h,
    const unsigned short* __restrict__ W1T, const float* __restrict__ b1,
    const float* __restrict__ W2, const float* __restrict__ b2,
    float* __restrict__ probs, int M)
{
    __shared__ unsigned short As[128 * LDST];
    const int tid = threadIdx.x;
    const int r0 = blockIdx.x * 128;
    {
        int rowi = tid >> 1, half = tid & 1;
        int gr = r0 + rowi; if (gr >= M) gr = M - 1;
        const float* gp = g + (size_t)gr * HD + half * 64;
        const float* hp = h + (size_t)gr * HD + half * 64;
        unsigned short* dst = As + rowi * LDST + half * 64;
        #pragma unroll
        for (int i = 0; i < 64; i += 4) {
            float4 gv = *(const float4*)(gp + i);
            float4 hv = *(const float4*)(hp + i);
            ushort4 o;
            float v;
            v = gv.x > 0.f ? gv.x : gv.x * NEG; o.x = f2bf(v + hv.x);
            v = gv.y > 0.f ? gv.y : gv.y * NEG; o.y = f2bf(v + hv.y);
            v = gv.z > 0.f ? gv.z : gv.z * NEG; o.z = f2bf(v + hv.z);
            v = gv.w > 0.f ? gv.w : gv.w * NEG; o.w = f2bf(v + hv.w);
            *(ushort4*)(dst + i) = o;
        }
    }
    __syncthreads();
    const int wave = tid >> 6, lane = tid & 63;
    const int m16 = lane & 15, quad = lane >> 4;
    floatx4 acc[2][8];
    #pragma unroll
    for (int i = 0; i < 2; i++)
        #pragma unroll
        for (int j = 0; j < 8; j++) acc[i][j] = (floatx4){0.f, 0.f, 0.f, 0.f};
    const unsigned short* a0 = As + (wave * 32 + m16) * LDST;
    const unsigned short* a1 = As + (wave * 32 + 16 + m16) * LDST;
    mm128(a0, a1, W1T, m16, quad, acc);
    #pragma unroll
    for (int rg = 0; rg < 2; rg++)
        #pragma unroll
        for (int i = 0; i < 4; i++) {
            float s = 0.f;
            #pragma unroll
            for (int cg = 0; cg < 8; cg++) {
                int c = cg * 16 + m16;
                float v = acc[rg][cg][i] + b1[c];
                v = v > 0.f ? v : v * NEG;
                s += v * W2[c];
            }
            s += __shfl_xor(s, 1); s += __shfl_xor(s, 2);
            s += __shfl_xor(s, 4); s += __shfl_xor(s, 8);
            int r = r0 + wave * 32 + rg * 16 + quad * 4 + i;
            if (m16 == 0 && r < M) probs[r] = sigm(s + b2[0]);
        }
}

// ---- weight prep: all casts/transposes in one kernel ----
__global__ void k_prep_w(const float* __restrict__ W_gcn, const float* __restrict__ W_gg,
                         const float* __restrict__ W_ih, const float* __restrict__ W_hh,
                         const float* __restrict__ W1, unsigned short* __restrict__ Wq) {
    int i = blockIdx.x * blockDim.x + threadIdx.x;
    if (i >= 180224) return;
    float v;
    if (i < 16384) {
        int n = i >> 7, k = i & 127;
        v = W_gcn[k * 128 + n];
    } else if (i < 65536) {
        int j = i - 16384;
        int l = j >> 14, rr = j & 16383;
        int n = rr >> 7, k = rr & 127;
        v = W_gg[l * 16384 + k * 128 + n];
    } else if (i < 114688) {
        v = W_ih[i - 65536];
    } else if (i < 163840) {
        v = W_hh[i - 114688];
    } else {
        int j = i - 163840;
        int n = j >> 7, k = j & 127;
        v = W1[k * 128 + n];
    }
    Wq[i] = f2bf(v);
}

__global__ void k_cast_x(const float* __restrict__ s, unsigned short* __restrict__ d, int n2) {
    int i = blockIdx.x * blockDim.x + threadIdx.x;
    if (i >= n2) return;
    float2 v = *(const float2*)(s + (size_t)i * 2);
    unsigned int p = (unsigned int)f2bf(v.x) | ((unsigned int)f2bf(v.y) << 16);
    *(unsigned int*)(d + (size_t)i * 2) = p;
}

// ---- CSR build ----
__global__ void k_hist(const int* __restrict__ row, const int* __restrict__ col,
                       int* __restrict__ cnt, int* __restrict__ degout,
                       int* __restrict__ rank, int E) {
    int e = blockIdx.x * blockDim.x + threadIdx.x;
    if (e < E) {
        rank[e] = atomicAdd(&cnt[col[e]], 1);
        atomicAdd(&degout[row[e]], 1);
    }
}

#define SCHUNK 2048
__global__ __launch_bounds__(256) void k_scan1(const int* __restrict__ cnt,
                                               int* __restrict__ excl,
                                               int* __restrict__ bsum, int N) {
    __shared__ int ts[256];
    int t = threadIdx.x;
    int base = blockIdx.x * SCHUNK + t * 8;
    int v[8]; int s = 0;
    #pragma unroll
    for (int q = 0; q < 8; q++) { int i = base + q; v[q] = (i < N) ? cnt[i] : 0; s += v[q]; }
    ts[t] = s;
    __syncthreads();
    for (int off = 1; off < 256; off <<= 1) {
        int a = (t >= off) ? ts[t - off] : 0;
        __syncthreads();
        ts[t] += a;
        __syncthreads();
    }
    int run = ts[t] - s;
    #pragma unroll
    for (int q = 0; q < 8; q++) { int i = base + q; if (i < N) excl[i] = run; run += v[q]; }
    if (t == 255) bsum[blockIdx.x] = ts[255];
}

__global__ void k_scan2(int* bsum, int nb) {
    if (threadIdx.x == 0) {
        int run = 0;
        for (int b = 0; b < nb; b++) { int v = bsum[b]; bsum[b] = run; run += v; }
    }
}

__global__ void k_csrfin(const int* __restrict__ excl, const int* __restrict__ bsum,
                         const int* __restrict__ cnt, const int* __restrict__ degout_i,
                         int* __restrict__ offs, float* __restrict__ dinv,
                         float* __restrict__ degout_f, int N, int E) {
    int i = blockIdx.x * blockDim.x + threadIdx.x;
    if (i >= N) return;
    offs[i] = excl[i] + bsum[i >> 11];
    if (i == 0) offs[N] = E;
    dinv[i] = rsqrtf((float)cnt[i] + 1.f);
    degout_f[i] = (float)degout_i[i];
}

__global__ void k_fill(const int* __restrict__ row, const int* __restrict__ col,
                       const int* __restrict__ offs, const int* __restrict__ rank,
                       int* __restrict__ csr_rows, int E) {
    int e = blockIdx.x * blockDim.x + threadIdx.x;
    if (e >= E) return;
    csr_rows[offs[col[e]] + rank[e]] = row[e];
}

// ---- GCN: gather + self-loop + bias + leaky, fused; writes h fp32 + g bf16 ----
__global__ __launch_bounds__(256) void k_gather_gcn(
    const unsigned short* __restrict__ src, const float* __restrict__ xw,
    const int* __restrict__ csr, const int* __restrict__ offs,
    const float* __restrict__ dinv, const float* __restrict__ bias,
    float* __restrict__ h, unsigned short* __restrict__ g16, int N)
{
    int node = blockIdx.x * 4 + (threadIdx.x >> 6);
    if (node >= N) return;
    int lane = threadIdx.x & 63;
    int s = offs[node], e = offs[node + 1];
    float ax = 0.f, ay = 0.f;
    int j = s;
    for (; j + 4 <= e; j += 4) {
        int r0 = csr[j], r1 = csr[j + 1], r2 = csr[j + 2], r3 = csr[j + 3];
        unsigned int u0 = *(const unsigned int*)(src + (size_t)r0 * HD + lane * 2);
        unsigned int u1 = *(const unsigned int*)(src + (size_t)r1 * HD + lane * 2);
        unsigned int u2 = *(const unsigned int*)(src + (size_t)r2 * HD + lane * 2);
        unsigned int u3 = *(const unsigned int*)(src + (size_t)r3 * HD + lane * 2);
        float s0 = dinv[r0], s1 = dinv[r1], s2 = dinv[r2], s3 = dinv[r3];
        ax += __uint_as_float(u0 << 16) * s0 + __uint_as_float(u1 << 16) * s1
            + __uint_as_float(u2 << 16) * s2 + __uint_as_float(u3 << 16) * s3;
        ay += __uint_as_float(u0 & 0xffff0000u) * s0 + __uint_as_float(u1 & 0xffff0000u) * s1
            + __uint_as_float(u2 & 0xffff0000u) * s2 + __uint_as_float(u3 & 0xffff0000u) * s3;
    }
    for (; j < e; j++) {
        int r = csr[j];
        unsigned int u = *(const unsigned int*)(src + (size_t)r * HD + lane * 2);
        float sc = dinv[r];
        ax += __uint_as_float(u << 16) * sc;
        ay += __uint_as_float(u & 0xffff0000u) * sc;
    }
    float dn = dinv[node];
    float dv2 = dn * dn;
    size_t i = (size_t)node * HD + lane * 2;
    float v0 = ax * dn + xw[i] * dv2 + bias[lane * 2];
    float v1 = ay * dn + xw[i + 1] * dv2 + bias[lane * 2 + 1];
    v0 = v0 > 0.f ? v0 : v0 * NEG;
    v1 = v1 > 0.f ? v1 : v1 * NEG;
    h[i] = v0; h[i + 1] = v1;
    *(unsigned int*)(g16 + i) = (unsigned int)f2bf(v0) | ((unsigned int)f2bf(v1) << 16);
}

// ---- layer gather (sum, no norm), bf16 in/out ----
__global__ __launch_bounds__(256) void k_gather_m(
    const unsigned short* __restrict__ src, const int* __restrict__ csr,
    const int* __restrict__ offs, unsigned short* __restrict__ out16, int N)
{
    int node = blockIdx.x * 4 + (threadIdx.x >> 6);
    if (node >= N) return;
    int lane = threadIdx.x & 63;
    int s = offs[node], e = offs[node + 1];
    float ax = 0.f, ay = 0.f;
    int j = s;
    for (; j + 4 <= e; j += 4) {
        int r0 = csr[j], r1 = csr[j + 1], r2 = csr[j + 2], r3 = csr[j + 3];
        unsigned int u0 = *(const unsigned int*)(src + (size_t)r0 * HD + lane * 2);
        unsigned int u1 = *(const unsigned int*)(src + (size_t)r1 * HD + lane * 2);
        unsigned int u2 = *(const unsigned int*)(src + (size_t)r2 * HD + lane * 2);
        unsigned int u3 = *(const unsigned int*)(src + (size_t)r3 * HD + lane * 2);
        ax += __uint_as_float(u0 << 16) + __uint_as_float(u1 << 16)
            + __uint_as_float(u2 << 16) + __uint_as_float(u3 << 16);
        ay += __uint_as_float(u0 & 0xffff0000u) + __uint_as_float(u1 & 0xffff0000u)
            + __uint_as_float(u2 & 0xffff0000u) + __uint_as_float(u3 & 0xffff0000u);
    }
    for (; j < e; j++) {
        int r = csr[j];
        unsigned int u = *(const unsigned int*)(src + (size_t)r * HD + lane * 2);
        ax += __uint_as_float(u << 16);
        ay += __uint_as_float(u & 0xffff0000u);
    }
    unsigned int p = (unsigned int)f2bf(ax) | ((unsigned int)f2bf(ay) << 16);
    *(unsigned int*)(out16 + (size_t)node * HD + lane * 2) = p;
}

__global__ __launch_bounds__(256) void k_loss_node(const float* __restrict__ probs,
                                                   const float* __restrict__ deg_out,
                                                   const int* __restrict__ batch,
                                                   float* __restrict__ ed, int N) {
    __shared__ float buck[GD];
    if (threadIdx.x < GD) buck[threadIdx.x] = 0.f;
    __syncthreads();
    for (int i = blockIdx.x * blockDim.x + threadIdx.x; i < N; i += gridDim.x * blockDim.x) {
        atomicAdd(&buck[batch[i]], probs[i] * deg_out[i]);
    }
    __syncthreads();
    if (threadIdx.x < GD) atomicAdd(&ed[threadIdx.x], buck[threadIdx.x]);
}

__global__ __launch_bounds__(256) void k_loss_edge(const float* __restrict__ probs,
                                                   const int* __restrict__ row,
                                                   const int* __restrict__ col,
                                                   const int* __restrict__ batch,
                                                   float* __restrict__ ew, int E) {
    __shared__ float buck[GD];
    if (threadIdx.x < GD) buck[threadIdx.x] = 0.f;
    __syncthreads();
    for (int e = blockIdx.x * blockDim.x + threadIdx.x; e < E; e += gridDim.x * blockDim.x) {
        atomicAdd(&buck[batch[row[e]]], probs[row[e]] * probs[col[e]]);
    }
    __syncthreads();
    if (threadIdx.x < GD) atomicAdd(&ew[threadIdx.x], buck[threadIdx.x]);
}

__global__ void k_finalize(const float* __restrict__ ed, const float* __restrict__ ew,
                           float* __restrict__ out) {
    int g = threadIdx.x;
    if (g < GD) out[g] = -(ed[g] - ew[g]) * 0.5f;
}

extern "C" void kernel_launch(void* const* d_in, const int* in_sizes, int n_in,
                              void* d_out, int out_size, void* d_ws, size_t ws_size,
                              hipStream_t stream) {
    const float* x     = (const float*)d_in[0];
    const int*   ei    = (const int*)d_in[1];
    const int*   batch = (const int*)d_in[2];
    const float* W_gcn = (const float*)d_in[3];
    const float* b_gcn = (const float*)d_in[4];
    const float* W_gg  = (const float*)d_in[5];
    const float* W_ih  = (const float*)d_in[6];
    const float* W_hh  = (const float*)d_in[7];
    const float* b_ih  = (const float*)d_in[8];
    const float* b_hh  = (const float*)d_in[9];
    const float* W1    = (const float*)d_in[10];
    const float* b1    = (const float*)d_in[11];
    const float* W2    = (const float*)d_in[12];
    const float* b2    = (const float*)d_in[13];
    float* out = (float*)d_out;

    const int N = in_sizes[2];
    const int E = in_sizes[1] / 2;
    const int* row = ei;
    const int* col = ei + E;
    const size_t NH = (size_t)N * HD;

    float* F = (float*)d_ws;
    float* f_h  = F + 0 * NH;
    float* f_g  = F + 1 * NH;
    float* f_xw = F + 2 * NH;
    unsigned short* U = (unsigned short*)(F + 3 * NH);
    unsigned short* x_bf = U;
    unsigned short* g_bf = U + 1 * NH;
    unsigned short* t_bf = U + 2 * NH;
    unsigned short* m_bf = U + 3 * NH;
    unsigned short* Wq   = U + 4 * NH;
    unsigned short* WgcnT = Wq;               // 16384
    unsigned short* WggT  = Wq + 16384;       // 3*16384
    unsigned short* Wih16 = Wq + 65536;       // 49152
    unsigned short* Whh16 = Wq + 114688;      // 49152
    unsigned short* W1T   = Wq + 163840;      // 16384
    float* S = (float*)(Wq + 180224);
    float* f_dinv   = S;
    float* f_degout = S + N;
    float* f_probs  = S + 2 * N;
    float* f_ed     = S + 3 * N;
    float* f_ew     = f_ed + GD;
    int* I = (int*)(f_ew + GD);
    int* i_cnt    = I;              // zeroed with i_degout (2N contiguous)
    int* i_degout = I + N;
    int* i_excl   = I + 2 * N;
    int* i_offs   = I + 3 * N;      // N+1
    int* i_bsum   = I + 4 * N + 8;  // <=64
    int* i_rank   = I + 4 * N + 128;
    int* i_csr    = i_rank + E;

    const int nb_scan = (N + SCHUNK - 1) / SCHUNK;
    const int gblocks = (N + 127) / 128;
    const int eg = (E + 255) / 256;
    const int ng = (N + 255) / 256;
    const int gather_grid = (N + 3) / 4;

    hipMemsetAsync(i_cnt, 0, sizeof(int) * 2 * (size_t)N, stream);
    hipMemsetAsync(f_ed, 0, sizeof(float) * 2 * GD, stream);

    // weight prep + input cast
    k_prep_w<<<704, 256, 0, stream>>>(W_gcn, W_gg, W_ih, W_hh, W1, Wq);
    k_cast_x<<<(int)((NH / 2 + 255) / 256), 256, 0, stream>>>(x, x_bf, (int)(NH / 2));

    // CSR build + degrees
    k_hist<<<eg, 256, 0, stream>>>(row, col, i_cnt, i_degout, i_rank, E);
    k_scan1<<<nb_scan, 256, 0, stream>>>(i_cnt, i_excl, i_bsum, N);
    k_scan2<<<1, 64, 0, stream>>>(i_bsum, nb_scan);
    k_csrfin<<<ng, 256, 0, stream>>>(i_excl, i_bsum, i_cnt, i_degout, i_offs,
                                     f_dinv, f_degout, N, E);
    k_fill<<<eg, 256, 0, stream>>>(row, col, i_offs, i_rank, i_csr, E);

    // GCN: xw = x @ W_gcn (fp32 + bf16); fused gather+finish -> h fp32, g bf16
    gemm_mfma<<<gblocks, 256, 0, stream>>>(x_bf, WgcnT, f_xw, t_bf, N);
    k_gather_gcn<<<gather_grid, 256, 0, stream>>>(t_bf, f_xw, i_csr, i_offs, f_dinv,
                                                  b_gcn, f_h, g_bf, N);

    // GatedGraphConv layers (fused gates + GRU)
    for (int l = 0; l < 3; l++) {
        gemm_mfma<<<gblocks, 256, 0, stream>>>(g_bf, WggT + (size_t)l * 16384,
                                               nullptr, t_bf, N);
        k_gather_m<<<gather_grid, 256, 0, stream>>>(t_bf, i_csr, i_offs, m_bf, N);
        k_gru_fused<<<gblocks, 256, 0, stream>>>(m_bf, g_bf, Wih16, Whh16, b_ih, b_hh,
                                                 (l == 0) ? f_h : f_g, f_g, g_bf, N);
    }

    // fused head
    k_head_fused<<<gblocks, 256, 0, stream>>>(f_g, f_h, W1T, b1, W2, b2, f_probs, N);

    // maxcut loss
    k_loss_node<<<512, 256, 0, stream>>>(f_probs, f_degout, batch, f_ed, N);
    k_loss_edge<<<1024, 256, 0, stream>>>(f_probs, row, col, batch, f_ew, E);
    k_finalize<<<1, 64, 0, stream>>>(f_ed, f_ew, out);
}